// Round 5
// baseline (937.729 us; speedup 1.0000x reference)
//
#include <hip/hip_runtime.h>

#define BATCH 16
#define NPTS 1024
#define CIN 16
#define NODES (BATCH*NPTS)      // 16384
#define KNN 10
#define EDGES (NODES*KNN)       // 163840
#define SLABF 1048576           // floats per output batch slab (1024*1024)

// Keep the harness template's kernel symbol defined (unused, zero-cost insurance).
__global__ void SetToGraphGNN_17351667876297_kernel() {}

__device__ __forceinline__ int uclamp(int v, int hi) {
    // clamps negatives and overshoots (unsigned trick)
    return ((unsigned)v > (unsigned)hi) ? hi : v;
}

// ---------------- zero scratch ints (cnt + cur, contiguous, 131072 B) ----------------
__global__ __launch_bounds__(256) void zero_ints(int* __restrict__ p) {
    int t = blockIdx.x * 256 + threadIdx.x;       // 32 blocks * 256 thr * int4 = 131072 B
    ((int4*)p)[t] = make_int4(0, 0, 0, 0);
}

// ---------------- KNN: top-10 nearest (excluding self), f32 input ----------------
// grid 64 blocks (batch*4), 256 threads, 1 node per thread.
__global__ __launch_bounds__(256) void knn_kernel(const float* __restrict__ xf,
                                                  int* __restrict__ nbors) {
    __shared__ float xs[512 * 16];
    __shared__ float sq[512];
    int tid = threadIdx.x;
    int bx = blockIdx.x;
    int batch = bx >> 2;
    int i_local = ((bx & 3) << 8) | tid;          // 0..1023
    const float* xbp = xf + batch * NPTS * CIN;

    const float4* xip = (const float4*)(xbp + i_local * 16);
    float4 xa = xip[0], xb4 = xip[1], xc = xip[2], xd = xip[3];
    float sqi = xa.x*xa.x + xa.y*xa.y + xa.z*xa.z + xa.w*xa.w
              + xb4.x*xb4.x + xb4.y*xb4.y + xb4.z*xb4.z + xb4.w*xb4.w
              + xc.x*xc.x + xc.y*xc.y + xc.z*xc.z + xc.w*xc.w
              + xd.x*xd.x + xd.y*xd.y + xd.z*xd.z + xd.w*xd.w;

    float bd[10]; int bi_[10];
#pragma unroll
    for (int r = 0; r < 10; ++r) { bd[r] = 3.0e38f; bi_[r] = 0; }

    for (int half = 0; half < 2; ++half) {
        __syncthreads();
        {
            int row = tid << 1;
            const float4* src = (const float4*)(xbp + ((half << 9) + row) * 16);
#pragma unroll
            for (int rr = 0; rr < 2; ++rr) {
                float4 a = src[rr*4+0], b = src[rr*4+1], c = src[rr*4+2], d = src[rr*4+3];
                float4* dstp = (float4*)(xs + (row + rr) * 16);
                dstp[0] = a; dstp[1] = b; dstp[2] = c; dstp[3] = d;
                sq[row + rr] = a.x*a.x + a.y*a.y + a.z*a.z + a.w*a.w
                             + b.x*b.x + b.y*b.y + b.z*b.z + b.w*b.w
                             + c.x*c.x + c.y*c.y + c.z*c.z + c.w*c.w
                             + d.x*d.x + d.y*d.y + d.z*d.z + d.w*d.w;
            }
        }
        __syncthreads();
        int jbase = half << 9;
        for (int jl = 0; jl < 512; ++jl) {
            const float4* yp = (const float4*)(xs + jl * 16);
            float4 ya = yp[0], yb = yp[1], yc = yp[2], yd = yp[3];
            float dot = ya.x*xa.x + ya.y*xa.y + ya.z*xa.z + ya.w*xa.w
                      + yb.x*xb4.x + yb.y*xb4.y + yb.z*xb4.z + yb.w*xb4.w
                      + yc.x*xc.x + yc.y*xc.y + yc.z*xc.z + yc.w*xc.w
                      + yd.x*xd.x + yd.y*xd.y + yd.z*xd.z + yd.w*xd.w;
            int j = jbase + jl;
            float dist = (sqi + sq[jl]) - 2.0f * dot;
            if (j != i_local && dist < bd[9]) {
                float cd = dist; int ci = j;
#pragma unroll
                for (int r = 0; r < 10; ++r) {
                    if (cd < bd[r]) {
                        float td = bd[r]; int ti = bi_[r];
                        bd[r] = cd; bi_[r] = ci;
                        cd = td; ci = ti;
                    }
                }
            }
        }
    }
    int gi = batch * NPTS + i_local;
#pragma unroll
    for (int r = 0; r < 10; ++r)
        nbors[gi * KNN + r] = batch * NPTS + uclamp(bi_[r], NPTS - 1);
}

// ---------------- reverse-CSR build ----------------
__global__ __launch_bounds__(256) void count_kernel(const int* __restrict__ nbors,
                                                    int* __restrict__ cnt) {
    int e = blockIdx.x * 256 + threadIdx.x;
    if (e < EDGES) {
        int dst = uclamp(nbors[e], NODES - 1);
        atomicAdd(&cnt[dst], 1);
    }
}

__global__ __launch_bounds__(256) void scan_kernel(const int* __restrict__ cnt,
                                                   int* __restrict__ rs) {
    __shared__ int part[256];
    int t = threadIdx.x;
    int base = t << 6;
    int s = 0;
    for (int u = 0; u < 64; ++u) s += cnt[base + u];
    part[t] = s;
    __syncthreads();
    for (int off = 1; off < 256; off <<= 1) {
        int v = (t >= off) ? part[t - off] : 0;
        __syncthreads();
        part[t] += v;
        __syncthreads();
    }
    int run = part[t] - s;
    for (int u = 0; u < 64; ++u) { rs[base + u] = run; run += cnt[base + u]; }
    if (t == 255) rs[NODES] = run;
}

__global__ __launch_bounds__(256) void fill_kernel(const int* __restrict__ nbors,
                                                   const int* __restrict__ rs,
                                                   int* __restrict__ cur,
                                                   int* __restrict__ esrc) {
    int e = blockIdx.x * 256 + threadIdx.x;
    if (e < EDGES) {
        int dst = uclamp(nbors[e], NODES - 1);
        int src = e / 10;                  // global source node index
        int pos = atomicAdd(&cur[dst], 1);
        int idx = uclamp(rs[dst] + pos, EDGES - 1);
        esrc[idx] = src;
    }
}

// ---------------- aggregation: agg[n,:] = sum_{e in in(n)} h[src_e,:] (f32) ----------------
__global__ __launch_bounds__(256) void agg_kernel(const float* __restrict__ hin,
                                                  float* __restrict__ agg,
                                                  const int* __restrict__ rs,
                                                  const int* __restrict__ esrc,
                                                  int din, int sh) {
    int gid = blockIdx.x * 256 + threadIdx.x;
    int n = gid >> sh;
    int c = (gid & ((1 << sh) - 1)) << 2;
    int e1 = uclamp(rs[n + 1], EDGES);
    int e0 = uclamp(rs[n], e1);
    float4 acc = {0.f, 0.f, 0.f, 0.f};
    for (int e = e0; e < e1; ++e) {
        int s = uclamp(esrc[e], NODES - 1);
        float4 v = *(const float4*)(hin + (size_t)s * din + c);
        acc.x += v.x; acc.y += v.y; acc.z += v.z; acc.w += v.w;
    }
    *(float4*)(agg + (size_t)n * din + c) = acc;
}

// ---------------- fused layer GEMM: Out = A1*W1^T + A2*W2^T + b (+relu), f32 ----------------
// 64x64 tile, 256 threads, 4x4 per thread, BK=16.
__global__ __launch_bounds__(256) void gemm_layer(const float* __restrict__ A1,
                                                  const float* __restrict__ A2,
                                                  const float* __restrict__ W1,
                                                  const float* __restrict__ W2,
                                                  const float* __restrict__ bias,
                                                  float* __restrict__ Out,
                                                  int Kdim, int Ndim, int relu) {
    __shared__ float As1[16 * 64], As2[16 * 64], Bs1[16 * 64], Bs2[16 * 64];
    int tid = threadIdx.x;
    int m0 = blockIdx.y * 64;
    int n0 = blockIdx.x * 64;
    int tx = tid & 15, ty = tid >> 4;
    int lr = tid >> 2;         // 0..63
    int lc = (tid & 3) << 2;   // 0,4,8,12
    float acc[4][4] = {};

    for (int k0 = 0; k0 < Kdim; k0 += 16) {
        __syncthreads();
        {
            float4 a = *(const float4*)(A1 + (size_t)(m0 + lr) * Kdim + k0 + lc);
            As1[(lc + 0) * 64 + lr] = a.x; As1[(lc + 1) * 64 + lr] = a.y;
            As1[(lc + 2) * 64 + lr] = a.z; As1[(lc + 3) * 64 + lr] = a.w;
            float4 b = *(const float4*)(A2 + (size_t)(m0 + lr) * Kdim + k0 + lc);
            As2[(lc + 0) * 64 + lr] = b.x; As2[(lc + 1) * 64 + lr] = b.y;
            As2[(lc + 2) * 64 + lr] = b.z; As2[(lc + 3) * 64 + lr] = b.w;
            float4 w1 = *(const float4*)(W1 + (size_t)(n0 + lr) * Kdim + k0 + lc);
            Bs1[(lc + 0) * 64 + lr] = w1.x; Bs1[(lc + 1) * 64 + lr] = w1.y;
            Bs1[(lc + 2) * 64 + lr] = w1.z; Bs1[(lc + 3) * 64 + lr] = w1.w;
            float4 w2 = *(const float4*)(W2 + (size_t)(n0 + lr) * Kdim + k0 + lc);
            Bs2[(lc + 0) * 64 + lr] = w2.x; Bs2[(lc + 1) * 64 + lr] = w2.y;
            Bs2[(lc + 2) * 64 + lr] = w2.z; Bs2[(lc + 3) * 64 + lr] = w2.w;
        }
        __syncthreads();
#pragma unroll
        for (int k = 0; k < 16; ++k) {
            float4 a1 = *(const float4*)(As1 + k * 64 + (ty << 2));
            float4 a2 = *(const float4*)(As2 + k * 64 + (ty << 2));
            float4 b1 = *(const float4*)(Bs1 + k * 64 + (tx << 2));
            float4 b2 = *(const float4*)(Bs2 + k * 64 + (tx << 2));
            float av1[4] = {a1.x, a1.y, a1.z, a1.w};
            float av2[4] = {a2.x, a2.y, a2.z, a2.w};
            float bv1[4] = {b1.x, b1.y, b1.z, b1.w};
            float bv2[4] = {b2.x, b2.y, b2.z, b2.w};
#pragma unroll
            for (int u = 0; u < 4; ++u)
#pragma unroll
                for (int v = 0; v < 4; ++v)
                    acc[u][v] += av1[u] * bv1[v] + av2[u] * bv2[v];
        }
    }
    float bv[4];
#pragma unroll
    for (int v = 0; v < 4; ++v) bv[v] = bias[n0 + (tx << 2) + v];
#pragma unroll
    for (int u = 0; u < 4; ++u) {
        int m = m0 + (ty << 2) + u;
        float4 o;
        o.x = acc[u][0] + bv[0]; o.y = acc[u][1] + bv[1];
        o.z = acc[u][2] + bv[2]; o.w = acc[u][3] + bv[3];
        if (relu) {
            o.x = fmaxf(o.x, 0.f); o.y = fmaxf(o.y, 0.f);
            o.z = fmaxf(o.z, 0.f); o.w = fmaxf(o.w, 0.f);
        }
        *(float4*)(Out + (size_t)m * Ndim + n0 + (tx << 2)) = o;
    }
}

// ---------------- final Gram: out[b,n,m] = sum_d h[b,n,d]*h[b,m,d], f32 ----------------
__global__ __launch_bounds__(256) void final_gemm(const float* __restrict__ H,
                                                  float* __restrict__ out) {
    __shared__ float As[64 * 64], Bs[64 * 64];   // [k][row]
    int tid = threadIdx.x;
    int bz = blockIdx.z;
    int n0 = blockIdx.y * 64;   // output row tile
    int m0 = blockIdx.x * 64;   // output col tile
    const float* Hb = H + (size_t)bz * NPTS * 64;
    int tx = tid & 15, ty = tid >> 4;
    int lr = tid >> 2;          // 0..63
    int lc = (tid & 3) << 4;    // 0,16,32,48 (col base, 16 cols each)
    float acc[4][4] = {};

    {
        const float4* sa = (const float4*)(Hb + (size_t)(n0 + lr) * 64 + lc);
        const float4* sb = (const float4*)(Hb + (size_t)(m0 + lr) * 64 + lc);
#pragma unroll
        for (int t4 = 0; t4 < 4; ++t4) {
            float4 a = sa[t4];
            int kc = lc + t4 * 4;
            As[(kc + 0) * 64 + lr] = a.x; As[(kc + 1) * 64 + lr] = a.y;
            As[(kc + 2) * 64 + lr] = a.z; As[(kc + 3) * 64 + lr] = a.w;
            float4 b = sb[t4];
            Bs[(kc + 0) * 64 + lr] = b.x; Bs[(kc + 1) * 64 + lr] = b.y;
            Bs[(kc + 2) * 64 + lr] = b.z; Bs[(kc + 3) * 64 + lr] = b.w;
        }
    }
    __syncthreads();
#pragma unroll 8
    for (int k = 0; k < 64; ++k) {
        float4 a = *(const float4*)(As + k * 64 + (ty << 2));
        float4 b = *(const float4*)(Bs + k * 64 + (tx << 2));
        float av[4] = {a.x, a.y, a.z, a.w};
        float bvv[4] = {b.x, b.y, b.z, b.w};
#pragma unroll
        for (int u = 0; u < 4; ++u)
#pragma unroll
            for (int v = 0; v < 4; ++v)
                acc[u][v] += av[u] * bvv[v];
    }
#pragma unroll
    for (int u = 0; u < 4; ++u) {
        int n = n0 + (ty << 2) + u;
        float4 o;
        o.x = acc[u][0]; o.y = acc[u][1]; o.z = acc[u][2]; o.w = acc[u][3];
        *(float4*)(out + ((size_t)(bz * NPTS + n)) * NPTS + m0 + (tx << 2)) = o;
    }
}

// ---------------- launch ----------------
extern "C" void kernel_launch(void* const* d_in, const int* in_sizes, int n_in,
                              void* d_out, int out_size, void* d_ws, size_t ws_size,
                              hipStream_t stream) {
    const float* x = (const float*)d_in[0];
    const float* W[12];
    for (int i = 0; i < 12; ++i) W[i] = (const float*)d_in[1 + i];
    // W[0]=W_root0 W[1]=W_rel0 W[2]=b0 | W[3..5]=layer1 | W[6..8]=layer2 | W[9..11]=layer3
    float* out = (float*)d_out;

    // d_ws: h4 first (16B-aligned), then graph structs. Total ~5.7 MB.
    char* w = (char*)d_ws;
    float* h4   = (float*)w;  w += (size_t)NODES * 64 * 4;          // 4 MB
    int* nbors  = (int*)w;    w += (size_t)EDGES * 4;               // 640 KB
    int* cnt    = (int*)w;    w += (size_t)NODES * 4;               // 64 KB
    int* cur    = (int*)w;    w += (size_t)NODES * 4;               // 64 KB
    int* rs     = (int*)w;    w += (size_t)(NODES + 1) * 4 + 12;    // 64 KB
    int* esrc   = (int*)w;    w += (size_t)EDGES * 4;               // 640 KB

    // Big activations live in d_out (64 MB, fully overwritten by final_gemm):
    float* agg = out;                          // 4 slabs = 16 MB (NODES*256 f32)
    float* hA  = out + (size_t)4 * SLABF;      // 16 MB
    float* hB  = out + (size_t)8 * SLABF;      // 16 MB

    SetToGraphGNN_17351667876297_kernel<<<1, 64, 0, stream>>>();

    knn_kernel<<<64, 256, 0, stream>>>(x, nbors);
    zero_ints<<<32, 256, 0, stream>>>(cnt);                 // zeroes cnt AND cur (contiguous)
    count_kernel<<<EDGES / 256, 256, 0, stream>>>(nbors, cnt);
    scan_kernel<<<1, 256, 0, stream>>>(cnt, rs);
    fill_kernel<<<EDGES / 256, 256, 0, stream>>>(nbors, rs, cur, esrc);

    // layer 0: K=16, N=128   (A = x; -> hA stride 128)
    agg_kernel<<<NODES * 4 / 256, 256, 0, stream>>>(x, agg, rs, esrc, 16, 2);
    gemm_layer<<<dim3(2, 256), 256, 0, stream>>>(x, agg, W[0], W[1], W[2], hA, 16, 128, 1);
    // layer 1: K=128, N=256  (hA -> hB)
    agg_kernel<<<NODES * 32 / 256, 256, 0, stream>>>(hA, agg, rs, esrc, 128, 5);
    gemm_layer<<<dim3(4, 256), 256, 0, stream>>>(hA, agg, W[3], W[4], W[5], hB, 128, 256, 1);
    // layer 2: K=256, N=256  (hB -> hA)
    agg_kernel<<<NODES * 64 / 256, 256, 0, stream>>>(hB, agg, rs, esrc, 256, 6);
    gemm_layer<<<dim3(4, 256), 256, 0, stream>>>(hB, agg, W[6], W[7], W[8], hA, 256, 256, 1);
    // layer 3: K=256, N=64, no relu  (hA -> h4 in d_ws)
    agg_kernel<<<NODES * 64 / 256, 256, 0, stream>>>(hA, agg, rs, esrc, 256, 6);
    gemm_layer<<<dim3(1, 256), 256, 0, stream>>>(hA, agg, W[9], W[10], W[11], h4, 256, 64, 0);

    final_gemm<<<dim3(16, 16, 16), 256, 0, stream>>>(h4, out);
}

// Round 6
// 608.659 us; speedup vs baseline: 1.5406x; 1.5406x over previous
//
#include <hip/hip_runtime.h>

#define BATCH 16
#define NPTS 1024
#define CIN 16
#define NODES (BATCH*NPTS)      // 16384
#define KNN 10
#define EDGES (NODES*KNN)       // 163840
#define SLABF 1048576           // floats per output batch slab (1024*1024)
#define JCH 8                   // j-chunks for KNN
#define JLEN (NPTS/JCH)         // 128

__device__ __forceinline__ int uclamp(int v, int hi) {
    return ((unsigned)v > (unsigned)hi) ? hi : v;
}

// ---------------- zero scratch ints (cnt + cur, contiguous, 131072 B) ----------------
__global__ __launch_bounds__(256) void zero_ints(int* __restrict__ p) {
    int t = blockIdx.x * 256 + threadIdx.x;
    ((int4*)p)[t] = make_int4(0, 0, 0, 0);
}

// ---------------- KNN phase A: per-(i, j-chunk) top-10 ----------------
// grid dim3(JCH, 4, BATCH), 256 threads; thread = node i, block covers 128 j's.
__global__ __launch_bounds__(256) void knn_partial(const float* __restrict__ xf,
                                                   float* __restrict__ pd,
                                                   int* __restrict__ pi_) {
    __shared__ float xs[JLEN * 16];   // 8 KB
    __shared__ float sq[JLEN];
    int jc = blockIdx.x, ic = blockIdx.y, b = blockIdx.z;
    int tid = threadIdx.x;
    int i_local = (ic << 8) | tid;                // 0..1023
    const float* xbp = xf + (size_t)b * NPTS * CIN;

    const float4* xip = (const float4*)(xbp + i_local * 16);
    float4 xa = xip[0], xb4 = xip[1], xc = xip[2], xd = xip[3];
    float sqi = xa.x*xa.x + xa.y*xa.y + xa.z*xa.z + xa.w*xa.w
              + xb4.x*xb4.x + xb4.y*xb4.y + xb4.z*xb4.z + xb4.w*xb4.w
              + xc.x*xc.x + xc.y*xc.y + xc.z*xc.z + xc.w*xc.w
              + xd.x*xd.x + xd.y*xd.y + xd.z*xd.z + xd.w*xd.w;

    // stage 128 j-rows: thread t stages 8 floats (half a row)
    int jbase = jc * JLEN;
    {
        int row = tid >> 1;
        int h8 = (tid & 1) << 3;
        const float4* src = (const float4*)(xbp + (jbase + row) * 16 + h8);
        float4 a = src[0], c = src[1];
        float4* dst = (float4*)(xs + row * 16 + h8);
        dst[0] = a; dst[1] = c;
    }
    __syncthreads();
    if (tid < JLEN) {
        const float4* rp = (const float4*)(xs + tid * 16);
        float4 a = rp[0], bq = rp[1], c = rp[2], d = rp[3];
        sq[tid] = a.x*a.x + a.y*a.y + a.z*a.z + a.w*a.w
                + bq.x*bq.x + bq.y*bq.y + bq.z*bq.z + bq.w*bq.w
                + c.x*c.x + c.y*c.y + c.z*c.z + c.w*c.w
                + d.x*d.x + d.y*d.y + d.z*d.z + d.w*d.w;
    }
    __syncthreads();

    float bd[10]; int bi_[10];
#pragma unroll
    for (int r = 0; r < 10; ++r) { bd[r] = 3.0e38f; bi_[r] = 0; }

    for (int jl = 0; jl < JLEN; ++jl) {
        const float4* yp = (const float4*)(xs + jl * 16);
        float4 ya = yp[0], yb = yp[1], yc = yp[2], yd = yp[3];
        // 4 independent accumulator chains (shorter dependency)
        float d0 = ya.x*xa.x  + ya.y*xa.y  + ya.z*xa.z  + ya.w*xa.w;
        float d1 = yb.x*xb4.x + yb.y*xb4.y + yb.z*xb4.z + yb.w*xb4.w;
        float d2 = yc.x*xc.x  + yc.y*xc.y  + yc.z*xc.z  + yc.w*xc.w;
        float d3 = yd.x*xd.x  + yd.y*xd.y  + yd.z*xd.z  + yd.w*xd.w;
        float dot = (d0 + d1) + (d2 + d3);
        int j = jbase + jl;
        float dist = (sqi + sq[jl]) - 2.0f * dot;
        if (j != i_local && dist < bd[9]) {
            float cd = dist; int ci = j;
#pragma unroll
            for (int r = 0; r < 10; ++r) {
                if (cd < bd[r]) {
                    float td = bd[r]; int ti = bi_[r];
                    bd[r] = cd; bi_[r] = ci;
                    cd = td; ci = ti;
                }
            }
        }
    }
    int base = (((b * JCH + jc) * NPTS) + i_local) * 10;
#pragma unroll
    for (int r = 0; r < 10; ++r) { pd[base + r] = bd[r]; pi_[base + r] = bi_[r]; }
}

// ---------------- KNN phase B: merge JCH sorted 10-lists per node ----------------
// 64 blocks x 256 threads = 16384 nodes.
__global__ __launch_bounds__(256) void knn_merge(const float* __restrict__ pd,
                                                 const int* __restrict__ pi_,
                                                 int* __restrict__ nbors) {
    int t = blockIdx.x * 256 + threadIdx.x;       // global node
    int b = t >> 10, i = t & 1023;
    float bd[10]; int bi_[10];
#pragma unroll
    for (int r = 0; r < 10; ++r) { bd[r] = 3.0e38f; bi_[r] = 0; }
    for (int jc = 0; jc < JCH; ++jc) {
        int base = (((b * JCH + jc) * NPTS) + i) * 10;
        for (int r = 0; r < 10; ++r) {
            float cd = pd[base + r];
            if (!(cd < bd[9])) break;             // chunk list ascending -> done
            int ci = pi_[base + r];
#pragma unroll
            for (int q = 0; q < 10; ++q) {
                if (cd < bd[q]) {
                    float td = bd[q]; int ti = bi_[q];
                    bd[q] = cd; bi_[q] = ci;
                    cd = td; ci = ti;
                }
            }
        }
    }
    int gi = b * NPTS + i;
#pragma unroll
    for (int r = 0; r < 10; ++r)
        nbors[gi * KNN + r] = b * NPTS + uclamp(bi_[r], NPTS - 1);
}

// ---------------- reverse-CSR build ----------------
__global__ __launch_bounds__(256) void count_kernel(const int* __restrict__ nbors,
                                                    int* __restrict__ cnt) {
    int e = blockIdx.x * 256 + threadIdx.x;
    if (e < EDGES) {
        int dst = uclamp(nbors[e], NODES - 1);
        atomicAdd(&cnt[dst], 1);
    }
}

__global__ __launch_bounds__(256) void scan_kernel(const int* __restrict__ cnt,
                                                   int* __restrict__ rs) {
    __shared__ int part[256];
    int t = threadIdx.x;
    int base = t << 6;
    int s = 0;
    for (int u = 0; u < 64; ++u) s += cnt[base + u];
    part[t] = s;
    __syncthreads();
    for (int off = 1; off < 256; off <<= 1) {
        int v = (t >= off) ? part[t - off] : 0;
        __syncthreads();
        part[t] += v;
        __syncthreads();
    }
    int run = part[t] - s;
    for (int u = 0; u < 64; ++u) { rs[base + u] = run; run += cnt[base + u]; }
    if (t == 255) rs[NODES] = run;
}

__global__ __launch_bounds__(256) void fill_kernel(const int* __restrict__ nbors,
                                                   const int* __restrict__ rs,
                                                   int* __restrict__ cur,
                                                   int* __restrict__ esrc) {
    int e = blockIdx.x * 256 + threadIdx.x;
    if (e < EDGES) {
        int dst = uclamp(nbors[e], NODES - 1);
        int src = e / 10;
        int pos = atomicAdd(&cur[dst], 1);
        int idx = uclamp(rs[dst] + pos, EDGES - 1);
        esrc[idx] = src;
    }
}

// ---------------- aggregation: agg[n,:] = sum_{e in in(n)} h[src_e,:] (f32) ----------------
__global__ __launch_bounds__(256) void agg_kernel(const float* __restrict__ hin,
                                                  float* __restrict__ agg,
                                                  const int* __restrict__ rs,
                                                  const int* __restrict__ esrc,
                                                  int din, int sh) {
    int gid = blockIdx.x * 256 + threadIdx.x;
    int n = gid >> sh;
    int c = (gid & ((1 << sh) - 1)) << 2;
    int e1 = uclamp(rs[n + 1], EDGES);
    int e0 = uclamp(rs[n], e1);
    float4 acc = {0.f, 0.f, 0.f, 0.f};
    for (int e = e0; e < e1; ++e) {
        int s = uclamp(esrc[e], NODES - 1);
        float4 v = *(const float4*)(hin + (size_t)s * din + c);
        acc.x += v.x; acc.y += v.y; acc.z += v.z; acc.w += v.w;
    }
    *(float4*)(agg + (size_t)n * din + c) = acc;
}

// ---------------- fused layer GEMM: Out = A1*W1^T + A2*W2^T + b (+relu), f32 ----------------
__global__ __launch_bounds__(256) void gemm_layer(const float* __restrict__ A1,
                                                  const float* __restrict__ A2,
                                                  const float* __restrict__ W1,
                                                  const float* __restrict__ W2,
                                                  const float* __restrict__ bias,
                                                  float* __restrict__ Out,
                                                  int Kdim, int Ndim, int relu) {
    __shared__ float As1[16 * 64], As2[16 * 64], Bs1[16 * 64], Bs2[16 * 64];
    int tid = threadIdx.x;
    int m0 = blockIdx.y * 64;
    int n0 = blockIdx.x * 64;
    int tx = tid & 15, ty = tid >> 4;
    int lr = tid >> 2;
    int lc = (tid & 3) << 2;
    float acc[4][4] = {};

    for (int k0 = 0; k0 < Kdim; k0 += 16) {
        __syncthreads();
        {
            float4 a = *(const float4*)(A1 + (size_t)(m0 + lr) * Kdim + k0 + lc);
            As1[(lc + 0) * 64 + lr] = a.x; As1[(lc + 1) * 64 + lr] = a.y;
            As1[(lc + 2) * 64 + lr] = a.z; As1[(lc + 3) * 64 + lr] = a.w;
            float4 b = *(const float4*)(A2 + (size_t)(m0 + lr) * Kdim + k0 + lc);
            As2[(lc + 0) * 64 + lr] = b.x; As2[(lc + 1) * 64 + lr] = b.y;
            As2[(lc + 2) * 64 + lr] = b.z; As2[(lc + 3) * 64 + lr] = b.w;
            float4 w1 = *(const float4*)(W1 + (size_t)(n0 + lr) * Kdim + k0 + lc);
            Bs1[(lc + 0) * 64 + lr] = w1.x; Bs1[(lc + 1) * 64 + lr] = w1.y;
            Bs1[(lc + 2) * 64 + lr] = w1.z; Bs1[(lc + 3) * 64 + lr] = w1.w;
            float4 w2 = *(const float4*)(W2 + (size_t)(n0 + lr) * Kdim + k0 + lc);
            Bs2[(lc + 0) * 64 + lr] = w2.x; Bs2[(lc + 1) * 64 + lr] = w2.y;
            Bs2[(lc + 2) * 64 + lr] = w2.z; Bs2[(lc + 3) * 64 + lr] = w2.w;
        }
        __syncthreads();
#pragma unroll
        for (int k = 0; k < 16; ++k) {
            float4 a1 = *(const float4*)(As1 + k * 64 + (ty << 2));
            float4 a2 = *(const float4*)(As2 + k * 64 + (ty << 2));
            float4 b1 = *(const float4*)(Bs1 + k * 64 + (tx << 2));
            float4 b2 = *(const float4*)(Bs2 + k * 64 + (tx << 2));
            float av1[4] = {a1.x, a1.y, a1.z, a1.w};
            float av2[4] = {a2.x, a2.y, a2.z, a2.w};
            float bv1[4] = {b1.x, b1.y, b1.z, b1.w};
            float bv2[4] = {b2.x, b2.y, b2.z, b2.w};
#pragma unroll
            for (int u = 0; u < 4; ++u)
#pragma unroll
                for (int v = 0; v < 4; ++v)
                    acc[u][v] += av1[u] * bv1[v] + av2[u] * bv2[v];
        }
    }
    float bv[4];
#pragma unroll
    for (int v = 0; v < 4; ++v) bv[v] = bias[n0 + (tx << 2) + v];
#pragma unroll
    for (int u = 0; u < 4; ++u) {
        int m = m0 + (ty << 2) + u;
        float4 o;
        o.x = acc[u][0] + bv[0]; o.y = acc[u][1] + bv[1];
        o.z = acc[u][2] + bv[2]; o.w = acc[u][3] + bv[3];
        if (relu) {
            o.x = fmaxf(o.x, 0.f); o.y = fmaxf(o.y, 0.f);
            o.z = fmaxf(o.z, 0.f); o.w = fmaxf(o.w, 0.f);
        }
        *(float4*)(Out + (size_t)m * Ndim + n0 + (tx << 2)) = o;
    }
}

// ---------------- final Gram: out[b,n,m] = sum_d h[b,n,d]*h[b,m,d], f32 ----------------
__global__ __launch_bounds__(256) void final_gemm(const float* __restrict__ H,
                                                  float* __restrict__ out) {
    __shared__ float As[64 * 64], Bs[64 * 64];
    int tid = threadIdx.x;
    int bz = blockIdx.z;
    int n0 = blockIdx.y * 64;
    int m0 = blockIdx.x * 64;
    const float* Hb = H + (size_t)bz * NPTS * 64;
    int tx = tid & 15, ty = tid >> 4;
    int lr = tid >> 2;
    int lc = (tid & 3) << 4;
    float acc[4][4] = {};

    {
        const float4* sa = (const float4*)(Hb + (size_t)(n0 + lr) * 64 + lc);
        const float4* sb = (const float4*)(Hb + (size_t)(m0 + lr) * 64 + lc);
#pragma unroll
        for (int t4 = 0; t4 < 4; ++t4) {
            float4 a = sa[t4];
            int kc = lc + t4 * 4;
            As[(kc + 0) * 64 + lr] = a.x; As[(kc + 1) * 64 + lr] = a.y;
            As[(kc + 2) * 64 + lr] = a.z; As[(kc + 3) * 64 + lr] = a.w;
            float4 b = sb[t4];
            Bs[(kc + 0) * 64 + lr] = b.x; Bs[(kc + 1) * 64 + lr] = b.y;
            Bs[(kc + 2) * 64 + lr] = b.z; Bs[(kc + 3) * 64 + lr] = b.w;
        }
    }
    __syncthreads();
#pragma unroll 8
    for (int k = 0; k < 64; ++k) {
        float4 a = *(const float4*)(As + k * 64 + (ty << 2));
        float4 b = *(const float4*)(Bs + k * 64 + (tx << 2));
        float av[4] = {a.x, a.y, a.z, a.w};
        float bvv[4] = {b.x, b.y, b.z, b.w};
#pragma unroll
        for (int u = 0; u < 4; ++u)
#pragma unroll
            for (int v = 0; v < 4; ++v)
                acc[u][v] += av[u] * bvv[v];
    }
#pragma unroll
    for (int u = 0; u < 4; ++u) {
        int n = n0 + (ty << 2) + u;
        float4 o;
        o.x = acc[u][0]; o.y = acc[u][1]; o.z = acc[u][2]; o.w = acc[u][3];
        *(float4*)(out + ((size_t)(bz * NPTS + n)) * NPTS + m0 + (tx << 2)) = o;
    }
}

// ---------------- launch ----------------
extern "C" void kernel_launch(void* const* d_in, const int* in_sizes, int n_in,
                              void* d_out, int out_size, void* d_ws, size_t ws_size,
                              hipStream_t stream) {
    const float* x = (const float*)d_in[0];
    const float* W[12];
    for (int i = 0; i < 12; ++i) W[i] = (const float*)d_in[1 + i];
    float* out = (float*)d_out;

    // d_ws: h4 + graph structs (~5.7 MB, proven safe in round 5).
    char* w = (char*)d_ws;
    float* h4   = (float*)w;  w += (size_t)NODES * 64 * 4;          // 4 MB
    int* nbors  = (int*)w;    w += (size_t)EDGES * 4;               // 640 KB
    int* cnt    = (int*)w;    w += (size_t)NODES * 4;               // 64 KB
    int* cur    = (int*)w;    w += (size_t)NODES * 4;               // 64 KB
    int* rs     = (int*)w;    w += (size_t)(NODES + 1) * 4 + 12;    // 64 KB
    int* esrc   = (int*)w;    w += (size_t)EDGES * 4;               // 640 KB

    // Big activations live in d_out (64 MB, fully overwritten by final_gemm):
    float* agg = out;                          // slabs 0..3 (16 MB)
    float* hA  = out + (size_t)4 * SLABF;      // slabs 4..7
    float* hB  = out + (size_t)8 * SLABF;      // slabs 8..11
    // KNN partial scratch also in d_out (dead before agg_kernel runs):
    float* pd  = out;                          // 16*8*1024*10 f32 = 5.24 MB
    int*   pi_ = (int*)(out + (size_t)2 * SLABF);   // 5.24 MB at +8 MB

    knn_partial<<<dim3(JCH, 4, BATCH), 256, 0, stream>>>(x, pd, pi_);
    knn_merge<<<64, 256, 0, stream>>>(pd, pi_, nbors);
    zero_ints<<<32, 256, 0, stream>>>(cnt);                 // zeroes cnt AND cur
    count_kernel<<<EDGES / 256, 256, 0, stream>>>(nbors, cnt);
    scan_kernel<<<1, 256, 0, stream>>>(cnt, rs);
    fill_kernel<<<EDGES / 256, 256, 0, stream>>>(nbors, rs, cur, esrc);

    // layer 0: K=16, N=128
    agg_kernel<<<NODES * 4 / 256, 256, 0, stream>>>(x, agg, rs, esrc, 16, 2);
    gemm_layer<<<dim3(2, 256), 256, 0, stream>>>(x, agg, W[0], W[1], W[2], hA, 16, 128, 1);
    // layer 1: K=128, N=256
    agg_kernel<<<NODES * 32 / 256, 256, 0, stream>>>(hA, agg, rs, esrc, 128, 5);
    gemm_layer<<<dim3(4, 256), 256, 0, stream>>>(hA, agg, W[3], W[4], W[5], hB, 128, 256, 1);
    // layer 2: K=256, N=256
    agg_kernel<<<NODES * 64 / 256, 256, 0, stream>>>(hB, agg, rs, esrc, 256, 6);
    gemm_layer<<<dim3(4, 256), 256, 0, stream>>>(hB, agg, W[6], W[7], W[8], hA, 256, 256, 1);
    // layer 3: K=256, N=64, no relu
    agg_kernel<<<NODES * 64 / 256, 256, 0, stream>>>(hA, agg, rs, esrc, 256, 6);
    gemm_layer<<<dim3(1, 256), 256, 0, stream>>>(hA, agg, W[9], W[10], W[11], h4, 256, 64, 0);

    final_gemm<<<dim3(16, 16, 16), 256, 0, stream>>>(h4, out);
}

// Round 7
// 428.014 us; speedup vs baseline: 2.1909x; 1.4221x over previous
//
#include <hip/hip_runtime.h>

#define BATCH 16
#define NPTS 1024
#define CIN 16
#define NODES (BATCH*NPTS)      // 16384
#define KNN 10
#define EDGES (NODES*KNN)       // 163840
#define JCH 8                   // j-chunks for KNN
#define JLEN (NPTS/JCH)         // 128

typedef unsigned short ushort_t;
typedef __attribute__((ext_vector_type(8))) short bf16x8;
typedef __attribute__((ext_vector_type(4))) float f32x4;

__device__ __forceinline__ int uclamp(int v, int hi) {
    return ((unsigned)v > (unsigned)hi) ? hi : v;
}
__device__ __forceinline__ float bf2f(ushort_t u) {
    union { unsigned int i; float f; } v; v.i = ((unsigned int)u) << 16; return v.f;
}
__device__ __forceinline__ ushort_t f2bf(float f) {
    union { float f; unsigned int i; } v; v.f = f;
    unsigned int r = (v.i + 0x7fffu + ((v.i >> 16) & 1u)) >> 16;
    return (ushort_t)r;
}

// ---------------- zero scratch ints ----------------
__global__ __launch_bounds__(256) void zero_ints(int* __restrict__ p) {
    int t = blockIdx.x * 256 + threadIdx.x;
    ((int4*)p)[t] = make_int4(0, 0, 0, 0);
}

// ---------------- cast layer-1..3 weights f32 -> bf16 (229376 elems) ----------------
// layout in dst: [W_root1 32768][W_rel1 32768][W_root2 65536][W_rel2 65536][W_root3 16384][W_rel3 16384]
__global__ __launch_bounds__(256) void cast_weights(const float* __restrict__ s0,
                                                    const float* __restrict__ s1,
                                                    const float* __restrict__ s2,
                                                    const float* __restrict__ s3,
                                                    const float* __restrict__ s4,
                                                    const float* __restrict__ s5,
                                                    ushort_t* __restrict__ dst) {
    int t = blockIdx.x * 256 + threadIdx.x;   // 896 blocks
    const float* s; int off;
    if      (t <  32768) { s = s0; off = 0; }
    else if (t <  65536) { s = s1; off = 32768; }
    else if (t < 131072) { s = s2; off = 65536; }
    else if (t < 196608) { s = s3; off = 131072; }
    else if (t < 212992) { s = s4; off = 196608; }
    else                 { s = s5; off = 212992; }
    dst[t] = f2bf(s[t - off]);
}

// ---------------- KNN phase A: per-(i, j-chunk) top-10, scalar-register top-k ----------------
#define INS(bdv, biv) { bool p = c < bdv; float tf = bdv; int ti = biv; \
    bdv = p ? c : bdv; biv = p ? cj : biv; c = p ? tf : c; cj = p ? ti : cj; }

__global__ __launch_bounds__(256, 2) void knn_partial(const float* __restrict__ xf,
                                                      float* __restrict__ pd,
                                                      int* __restrict__ pi_) {
    __shared__ float xs[JLEN * 16];   // 8 KB
    __shared__ float sq[JLEN];
    int jc = blockIdx.x, ic = blockIdx.y, b = blockIdx.z;
    int tid = threadIdx.x;
    int i_local = (ic << 8) | tid;
    const float* xbp = xf + (size_t)b * NPTS * CIN;

    const float4* xip = (const float4*)(xbp + i_local * 16);
    float4 xa = xip[0], xb4 = xip[1], xc = xip[2], xd = xip[3];
    float sqi = xa.x*xa.x + xa.y*xa.y + xa.z*xa.z + xa.w*xa.w
              + xb4.x*xb4.x + xb4.y*xb4.y + xb4.z*xb4.z + xb4.w*xb4.w
              + xc.x*xc.x + xc.y*xc.y + xc.z*xc.z + xc.w*xc.w
              + xd.x*xd.x + xd.y*xd.y + xd.z*xd.z + xd.w*xd.w;

    int jbase = jc * JLEN;
    {
        int row = tid >> 1;
        int h8 = (tid & 1) << 3;
        const float4* src = (const float4*)(xbp + (jbase + row) * 16 + h8);
        float4 a = src[0], c4 = src[1];
        float4* dst = (float4*)(xs + row * 16 + h8);
        dst[0] = a; dst[1] = c4;
    }
    __syncthreads();
    if (tid < JLEN) {
        const float4* rp = (const float4*)(xs + tid * 16);
        float4 a = rp[0], bq = rp[1], c4 = rp[2], d4 = rp[3];
        sq[tid] = a.x*a.x + a.y*a.y + a.z*a.z + a.w*a.w
                + bq.x*bq.x + bq.y*bq.y + bq.z*bq.z + bq.w*bq.w
                + c4.x*c4.x + c4.y*c4.y + c4.z*c4.z + c4.w*c4.w
                + d4.x*d4.x + d4.y*d4.y + d4.z*d4.z + d4.w*d4.w;
    }
    __syncthreads();

    float bd0=3.0e38f,bd1=3.0e38f,bd2=3.0e38f,bd3=3.0e38f,bd4=3.0e38f,
          bd5=3.0e38f,bd6=3.0e38f,bd7=3.0e38f,bd8=3.0e38f,bd9=3.0e38f;
    int   bi0=0,bi1=0,bi2=0,bi3=0,bi4=0,bi5=0,bi6=0,bi7=0,bi8=0,bi9=0;

    for (int jl = 0; jl < JLEN; ++jl) {
        const float4* yp = (const float4*)(xs + jl * 16);
        float4 ya = yp[0], yb = yp[1], yc = yp[2], yd = yp[3];
        float d0 = ya.x*xa.x  + ya.y*xa.y  + ya.z*xa.z  + ya.w*xa.w;
        float d1 = yb.x*xb4.x + yb.y*xb4.y + yb.z*xb4.z + yb.w*xb4.w;
        float d2 = yc.x*xc.x  + yc.y*xc.y  + yc.z*xc.z  + yc.w*xc.w;
        float d3 = yd.x*xd.x  + yd.y*xd.y  + yd.z*xd.z  + yd.w*xd.w;
        float dot = (d0 + d1) + (d2 + d3);
        int j = jbase + jl;
        float dist = (sqi + sq[jl]) - 2.0f * dot;
        float c = (j != i_local) ? dist : 3.0e38f;
        int cj = j;
        INS(bd0,bi0) INS(bd1,bi1) INS(bd2,bi2) INS(bd3,bi3) INS(bd4,bi4)
        INS(bd5,bi5) INS(bd6,bi6) INS(bd7,bi7) INS(bd8,bi8) INS(bd9,bi9)
    }
    int base = (((b * JCH + jc) * NPTS) + i_local) * 10;
    pd[base+0]=bd0; pd[base+1]=bd1; pd[base+2]=bd2; pd[base+3]=bd3; pd[base+4]=bd4;
    pd[base+5]=bd5; pd[base+6]=bd6; pd[base+7]=bd7; pd[base+8]=bd8; pd[base+9]=bd9;
    pi_[base+0]=bi0; pi_[base+1]=bi1; pi_[base+2]=bi2; pi_[base+3]=bi3; pi_[base+4]=bi4;
    pi_[base+5]=bi5; pi_[base+6]=bi6; pi_[base+7]=bi7; pi_[base+8]=bi8; pi_[base+9]=bi9;
}

// ---------------- KNN phase B: merge JCH sorted 10-lists per node ----------------
__global__ __launch_bounds__(256) void knn_merge(const float* __restrict__ pd,
                                                 const int* __restrict__ pi_,
                                                 int* __restrict__ nbors) {
    int t = blockIdx.x * 256 + threadIdx.x;
    int b = t >> 10, i = t & 1023;
    float bd[10]; int bi_[10];
#pragma unroll
    for (int r = 0; r < 10; ++r) { bd[r] = 3.0e38f; bi_[r] = 0; }
    for (int jc = 0; jc < JCH; ++jc) {
        int base = (((b * JCH + jc) * NPTS) + i) * 10;
        for (int r = 0; r < 10; ++r) {
            float cd = pd[base + r];
            if (!(cd < bd[9])) break;
            int ci = pi_[base + r];
#pragma unroll
            for (int q = 0; q < 10; ++q) {
                if (cd < bd[q]) {
                    float td = bd[q]; int ti = bi_[q];
                    bd[q] = cd; bi_[q] = ci;
                    cd = td; ci = ti;
                }
            }
        }
    }
    int gi = b * NPTS + i;
#pragma unroll
    for (int r = 0; r < 10; ++r)
        nbors[gi * KNN + r] = b * NPTS + uclamp(bi_[r], NPTS - 1);
}

// ---------------- reverse-CSR build ----------------
__global__ __launch_bounds__(256) void count_kernel(const int* __restrict__ nbors,
                                                    int* __restrict__ cnt) {
    int e = blockIdx.x * 256 + threadIdx.x;
    if (e < EDGES) atomicAdd(&cnt[uclamp(nbors[e], NODES - 1)], 1);
}

__global__ __launch_bounds__(256) void scan_kernel(const int* __restrict__ cnt,
                                                   int* __restrict__ rs) {
    __shared__ int part[256];
    int t = threadIdx.x;
    int base = t << 6;
    int s = 0;
    for (int u = 0; u < 64; ++u) s += cnt[base + u];
    part[t] = s;
    __syncthreads();
    for (int off = 1; off < 256; off <<= 1) {
        int v = (t >= off) ? part[t - off] : 0;
        __syncthreads();
        part[t] += v;
        __syncthreads();
    }
    int run = part[t] - s;
    for (int u = 0; u < 64; ++u) { rs[base + u] = run; run += cnt[base + u]; }
    if (t == 255) rs[NODES] = run;
}

__global__ __launch_bounds__(256) void fill_kernel(const int* __restrict__ nbors,
                                                   const int* __restrict__ rs,
                                                   int* __restrict__ cur,
                                                   int* __restrict__ esrc) {
    int e = blockIdx.x * 256 + threadIdx.x;
    if (e < EDGES) {
        int dst = uclamp(nbors[e], NODES - 1);
        int src = e / 10;
        int pos = atomicAdd(&cur[dst], 1);
        esrc[uclamp(rs[dst] + pos, EDGES - 1)] = src;
    }
}

// ---------------- aggregation f32 (layer 0 only, din=16) ----------------
__global__ __launch_bounds__(256) void agg_kernel(const float* __restrict__ hin,
                                                  float* __restrict__ agg,
                                                  const int* __restrict__ rs,
                                                  const int* __restrict__ esrc,
                                                  int din, int sh) {
    int gid = blockIdx.x * 256 + threadIdx.x;
    int n = gid >> sh;
    int c = (gid & ((1 << sh) - 1)) << 2;
    int e1 = uclamp(rs[n + 1], EDGES);
    int e0 = uclamp(rs[n], e1);
    float4 acc = {0.f, 0.f, 0.f, 0.f};
    for (int e = e0; e < e1; ++e) {
        int s = uclamp(esrc[e], NODES - 1);
        float4 v = *(const float4*)(hin + (size_t)s * din + c);
        acc.x += v.x; acc.y += v.y; acc.z += v.z; acc.w += v.w;
    }
    *(float4*)(agg + (size_t)n * din + c) = acc;
}

// ---------------- aggregation bf16 (layers 1-3) ----------------
__global__ __launch_bounds__(256) void agg_bf16(const ushort_t* __restrict__ hin,
                                                ushort_t* __restrict__ agg,
                                                const int* __restrict__ rs,
                                                const int* __restrict__ esrc,
                                                int din, int sh) {
    int gid = blockIdx.x * 256 + threadIdx.x;
    int n = gid >> sh;
    int c = (gid & ((1 << sh) - 1)) << 2;
    int e1 = uclamp(rs[n + 1], EDGES);
    int e0 = uclamp(rs[n], e1);
    float a0 = 0.f, a1 = 0.f, a2 = 0.f, a3 = 0.f;
    for (int e = e0; e < e1; ++e) {
        int s = uclamp(esrc[e], NODES - 1);
        ushort4 v = *(const ushort4*)(hin + (size_t)s * din + c);
        a0 += bf2f(v.x); a1 += bf2f(v.y); a2 += bf2f(v.z); a3 += bf2f(v.w);
    }
    ushort4 o; o.x = f2bf(a0); o.y = f2bf(a1); o.z = f2bf(a2); o.w = f2bf(a3);
    *(ushort4*)(agg + (size_t)n * din + c) = o;
}

// ---------------- layer-0 GEMM (f32 vector, K=16): Out = A1*W1^T + A2*W2^T + b, relu, bf16 out ----
__global__ __launch_bounds__(256) void gemm_layer0(const float* __restrict__ A1,
                                                   const float* __restrict__ A2,
                                                   const float* __restrict__ W1,
                                                   const float* __restrict__ W2,
                                                   const float* __restrict__ bias,
                                                   ushort_t* __restrict__ Out,
                                                   int Kdim, int Ndim) {
    __shared__ float As1[16 * 64], As2[16 * 64], Bs1[16 * 64], Bs2[16 * 64];
    int tid = threadIdx.x;
    int m0 = blockIdx.y * 64;
    int n0 = blockIdx.x * 64;
    int tx = tid & 15, ty = tid >> 4;
    int lr = tid >> 2;
    int lc = (tid & 3) << 2;
    float acc[4][4] = {};

    for (int k0 = 0; k0 < Kdim; k0 += 16) {
        __syncthreads();
        {
            float4 a = *(const float4*)(A1 + (size_t)(m0 + lr) * Kdim + k0 + lc);
            As1[(lc + 0) * 64 + lr] = a.x; As1[(lc + 1) * 64 + lr] = a.y;
            As1[(lc + 2) * 64 + lr] = a.z; As1[(lc + 3) * 64 + lr] = a.w;
            float4 b = *(const float4*)(A2 + (size_t)(m0 + lr) * Kdim + k0 + lc);
            As2[(lc + 0) * 64 + lr] = b.x; As2[(lc + 1) * 64 + lr] = b.y;
            As2[(lc + 2) * 64 + lr] = b.z; As2[(lc + 3) * 64 + lr] = b.w;
            float4 w1 = *(const float4*)(W1 + (size_t)(n0 + lr) * Kdim + k0 + lc);
            Bs1[(lc + 0) * 64 + lr] = w1.x; Bs1[(lc + 1) * 64 + lr] = w1.y;
            Bs1[(lc + 2) * 64 + lr] = w1.z; Bs1[(lc + 3) * 64 + lr] = w1.w;
            float4 w2 = *(const float4*)(W2 + (size_t)(n0 + lr) * Kdim + k0 + lc);
            Bs2[(lc + 0) * 64 + lr] = w2.x; Bs2[(lc + 1) * 64 + lr] = w2.y;
            Bs2[(lc + 2) * 64 + lr] = w2.z; Bs2[(lc + 3) * 64 + lr] = w2.w;
        }
        __syncthreads();
#pragma unroll
        for (int k = 0; k < 16; ++k) {
            float4 a1 = *(const float4*)(As1 + k * 64 + (ty << 2));
            float4 a2 = *(const float4*)(As2 + k * 64 + (ty << 2));
            float4 b1 = *(const float4*)(Bs1 + k * 64 + (tx << 2));
            float4 b2 = *(const float4*)(Bs2 + k * 64 + (tx << 2));
            float av1[4] = {a1.x, a1.y, a1.z, a1.w};
            float av2[4] = {a2.x, a2.y, a2.z, a2.w};
            float bv1[4] = {b1.x, b1.y, b1.z, b1.w};
            float bv2[4] = {b2.x, b2.y, b2.z, b2.w};
#pragma unroll
            for (int u = 0; u < 4; ++u)
#pragma unroll
                for (int v = 0; v < 4; ++v)
                    acc[u][v] += av1[u] * bv1[v] + av2[u] * bv2[v];
        }
    }
    float bv[4];
#pragma unroll
    for (int v = 0; v < 4; ++v) bv[v] = bias[n0 + (tx << 2) + v];
#pragma unroll
    for (int u = 0; u < 4; ++u) {
        int m = m0 + (ty << 2) + u;
        ushort4 o;
        o.x = f2bf(fmaxf(acc[u][0] + bv[0], 0.f));
        o.y = f2bf(fmaxf(acc[u][1] + bv[1], 0.f));
        o.z = f2bf(fmaxf(acc[u][2] + bv[2], 0.f));
        o.w = f2bf(fmaxf(acc[u][3] + bv[3], 0.f));
        *(ushort4*)(Out + (size_t)m * Ndim + n0 + (tx << 2)) = o;
    }
}

// ---------------- MFMA dual-GEMM (layers 1-3): Out = A1*W1^T + A2*W2^T + b (+relu) ----------------
// block = 4 waves; wave w: 16-row m-strip; 64-wide n-tile per block (4x 16x16 MFMA tiles).
// A[m][k]: lane holds A[m=ln&15][k = quad*8 + j]; B=W^T: lane holds W[n=ln&15][k=quad*8+j].
// D: row = quad*4 + reg, col = ln&15 (m89/m118-verified gfx950 layouts).
__global__ __launch_bounds__(256) void gemm_mfma(const ushort_t* __restrict__ A1,
                                                 const ushort_t* __restrict__ A2,
                                                 const ushort_t* __restrict__ W1,
                                                 const ushort_t* __restrict__ W2,
                                                 const float* __restrict__ bias,
                                                 void* __restrict__ outp,
                                                 int Kdim, int Ndim, int relu, int out_bf16) {
    int tid = threadIdx.x;
    int wave = tid >> 6, lane = tid & 63;
    int quad = lane >> 4, l16 = lane & 15;
    int ms = blockIdx.y * 64 + wave * 16;
    int n0 = blockIdx.x * 64;

    f32x4 acc0 = {0.f,0.f,0.f,0.f}, acc1 = acc0, acc2 = acc0, acc3 = acc0;
    const ushort_t* a1p = A1 + (size_t)(ms + l16) * Kdim + quad * 8;
    const ushort_t* a2p = A2 + (size_t)(ms + l16) * Kdim + quad * 8;
    const ushort_t* w1p = W1 + (size_t)(n0 + l16) * Kdim + quad * 8;
    const ushort_t* w2p = W2 + (size_t)(n0 + l16) * Kdim + quad * 8;
    size_t wstride = (size_t)16 * Kdim;

    for (int k0 = 0; k0 < Kdim; k0 += 32) {
        bf16x8 a1 = *(const bf16x8*)(a1p + k0);
        bf16x8 a2 = *(const bf16x8*)(a2p + k0);
        bf16x8 u0 = *(const bf16x8*)(w1p + k0);
        bf16x8 v0 = *(const bf16x8*)(w2p + k0);
        bf16x8 u1 = *(const bf16x8*)(w1p + wstride + k0);
        bf16x8 v1 = *(const bf16x8*)(w2p + wstride + k0);
        bf16x8 u2 = *(const bf16x8*)(w1p + 2*wstride + k0);
        bf16x8 v2 = *(const bf16x8*)(w2p + 2*wstride + k0);
        bf16x8 u3 = *(const bf16x8*)(w1p + 3*wstride + k0);
        bf16x8 v3 = *(const bf16x8*)(w2p + 3*wstride + k0);
        acc0 = __builtin_amdgcn_mfma_f32_16x16x32_bf16(a1, u0, acc0, 0, 0, 0);
        acc0 = __builtin_amdgcn_mfma_f32_16x16x32_bf16(a2, v0, acc0, 0, 0, 0);
        acc1 = __builtin_amdgcn_mfma_f32_16x16x32_bf16(a1, u1, acc1, 0, 0, 0);
        acc1 = __builtin_amdgcn_mfma_f32_16x16x32_bf16(a2, v1, acc1, 0, 0, 0);
        acc2 = __builtin_amdgcn_mfma_f32_16x16x32_bf16(a1, u2, acc2, 0, 0, 0);
        acc2 = __builtin_amdgcn_mfma_f32_16x16x32_bf16(a2, v2, acc2, 0, 0, 0);
        acc3 = __builtin_amdgcn_mfma_f32_16x16x32_bf16(a1, u3, acc3, 0, 0, 0);
        acc3 = __builtin_amdgcn_mfma_f32_16x16x32_bf16(a2, v3, acc3, 0, 0, 0);
    }

    f32x4 accs[4] = {acc0, acc1, acc2, acc3};
#pragma unroll
    for (int nt = 0; nt < 4; ++nt) {
        int n = n0 + nt * 16 + l16;
        float bb = bias[n];
#pragma unroll
        for (int r = 0; r < 4; ++r) {
            float v = accs[nt][r] + bb;
            if (relu) v = fmaxf(v, 0.f);
            int m = ms + quad * 4 + r;
            if (out_bf16) ((ushort_t*)outp)[(size_t)m * Ndim + n] = f2bf(v);
            else          ((float*)outp)[(size_t)m * Ndim + n] = v;
        }
    }
}

// ---------------- final Gram: out[b,n,m] = sum_d h[b,n,d]*h[b,m,d], f32 ----------------
__global__ __launch_bounds__(256) void final_gemm(const float* __restrict__ H,
                                                  float* __restrict__ out) {
    __shared__ float As[64 * 64], Bs[64 * 64];
    int tid = threadIdx.x;
    int bz = blockIdx.z;
    int n0 = blockIdx.y * 64;
    int m0 = blockIdx.x * 64;
    const float* Hb = H + (size_t)bz * NPTS * 64;
    int tx = tid & 15, ty = tid >> 4;
    int lr = tid >> 2;
    int lc = (tid & 3) << 4;
    float acc[4][4] = {};

    {
        const float4* sa = (const float4*)(Hb + (size_t)(n0 + lr) * 64 + lc);
        const float4* sb = (const float4*)(Hb + (size_t)(m0 + lr) * 64 + lc);
#pragma unroll
        for (int t4 = 0; t4 < 4; ++t4) {
            float4 a = sa[t4];
            int kc = lc + t4 * 4;
            As[(kc + 0) * 64 + lr] = a.x; As[(kc + 1) * 64 + lr] = a.y;
            As[(kc + 2) * 64 + lr] = a.z; As[(kc + 3) * 64 + lr] = a.w;
            float4 b = sb[t4];
            Bs[(kc + 0) * 64 + lr] = b.x; Bs[(kc + 1) * 64 + lr] = b.y;
            Bs[(kc + 2) * 64 + lr] = b.z; Bs[(kc + 3) * 64 + lr] = b.w;
        }
    }
    __syncthreads();
#pragma unroll 8
    for (int k = 0; k < 64; ++k) {
        float4 a = *(const float4*)(As + k * 64 + (ty << 2));
        float4 b = *(const float4*)(Bs + k * 64 + (tx << 2));
        float av[4] = {a.x, a.y, a.z, a.w};
        float bvv[4] = {b.x, b.y, b.z, b.w};
#pragma unroll
        for (int u = 0; u < 4; ++u)
#pragma unroll
            for (int v = 0; v < 4; ++v)
                acc[u][v] += av[u] * bvv[v];
    }
#pragma unroll
    for (int u = 0; u < 4; ++u) {
        int n = n0 + (ty << 2) + u;
        float4 o;
        o.x = acc[u][0]; o.y = acc[u][1]; o.z = acc[u][2]; o.w = acc[u][3];
        *(float4*)(out + ((size_t)(bz * NPTS + n)) * NPTS + m0 + (tx << 2)) = o;
    }
}

// ---------------- launch ----------------
extern "C" void kernel_launch(void* const* d_in, const int* in_sizes, int n_in,
                              void* d_out, int out_size, void* d_ws, size_t ws_size,
                              hipStream_t stream) {
    const float* x = (const float*)d_in[0];
    const float* W[12];
    for (int i = 0; i < 12; ++i) W[i] = (const float*)d_in[1 + i];
    float* out = (float*)d_out;

    // d_ws (~5.5 MB, proven safe): h4 + graph structs
    char* w = (char*)d_ws;
    float* h4   = (float*)w;  w += (size_t)NODES * 64 * 4;          // 4 MB
    int* nbors  = (int*)w;    w += (size_t)EDGES * 4;               // 640 KB
    int* cnt    = (int*)w;    w += (size_t)NODES * 4;               // 64 KB
    int* cur    = (int*)w;    w += (size_t)NODES * 4;               // 64 KB
    int* rs     = (int*)w;    w += (size_t)(NODES + 1) * 4 + 12;    // 64 KB
    int* esrc   = (int*)w;    w += (size_t)EDGES * 4;               // 640 KB

    // scratch inside d_out (64 MB, fully overwritten by final_gemm):
    char* ob = (char*)d_out;
    ushort_t* aggb  = (ushort_t*)(ob + 0);                  // 8 MB (bf16 agg, max din=256)
    ushort_t* h1b   = (ushort_t*)(ob + (size_t) 8u*1048576);// 4 MB
    ushort_t* h2b   = (ushort_t*)(ob + (size_t)12u*1048576);// 8 MB
    ushort_t* h3b   = (ushort_t*)(ob + (size_t)20u*1048576);// 8 MB
    float*    agg0f = (float*)   (ob + (size_t)28u*1048576);// 1 MB (f32 agg, din=16)
    ushort_t* wb    = (ushort_t*)(ob + (size_t)29u*1048576);// 448 KB bf16 weights
    float*    pd    = (float*)   (ob + (size_t)30u*1048576);// 5.25 MB
    int*      pi_   = (int*)     (ob + (size_t)36u*1048576);// 5.25 MB

    cast_weights<<<896, 256, 0, stream>>>(W[3], W[4], W[6], W[7], W[9], W[10], wb);
    knn_partial<<<dim3(JCH, 4, BATCH), 256, 0, stream>>>(x, pd, pi_);
    knn_merge<<<64, 256, 0, stream>>>(pd, pi_, nbors);
    zero_ints<<<32, 256, 0, stream>>>(cnt);
    count_kernel<<<EDGES / 256, 256, 0, stream>>>(nbors, cnt);
    scan_kernel<<<1, 256, 0, stream>>>(cnt, rs);
    fill_kernel<<<EDGES / 256, 256, 0, stream>>>(nbors, rs, cur, esrc);

    // layer 0: K=16, N=128, f32 compute, bf16 out
    agg_kernel<<<NODES * 4 / 256, 256, 0, stream>>>(x, agg0f, rs, esrc, 16, 2);
    gemm_layer0<<<dim3(2, 256), 256, 0, stream>>>(x, agg0f, W[0], W[1], W[2], h1b, 16, 128);
    // layer 1: K=128, N=256, MFMA
    agg_bf16<<<NODES * 32 / 256, 256, 0, stream>>>(h1b, aggb, rs, esrc, 128, 5);
    gemm_mfma<<<dim3(4, 256), 256, 0, stream>>>(h1b, aggb, wb, wb + 32768, W[5],
                                                h2b, 128, 256, 1, 1);
    // layer 2: K=256, N=256, MFMA
    agg_bf16<<<NODES * 64 / 256, 256, 0, stream>>>(h2b, aggb, rs, esrc, 256, 6);
    gemm_mfma<<<dim3(4, 256), 256, 0, stream>>>(h2b, aggb, wb + 65536, wb + 131072, W[8],
                                                h3b, 256, 256, 1, 1);
    // layer 3: K=256, N=64, MFMA, no relu, f32 out
    agg_bf16<<<NODES * 64 / 256, 256, 0, stream>>>(h3b, aggb, rs, esrc, 256, 6);
    gemm_mfma<<<dim3(1, 256), 256, 0, stream>>>(h3b, aggb, wb + 196608, wb + 212992, W[11],
                                                h4, 256, 64, 0, 0);

    final_gemm<<<dim3(16, 16, 16), 256, 0, stream>>>(h4, out);
}